// Round 1
// baseline (1101.604 us; speedup 1.0000x reference)
//
#include <hip/hip_runtime.h>
#include <cstdint>

using half_t = _Float16;
using half8  = __attribute__((ext_vector_type(8))) _Float16;
using half4v = __attribute__((ext_vector_type(4))) _Float16;
using f32x4  = __attribute__((ext_vector_type(4))) float;
using flt4v  = __attribute__((ext_vector_type(4))) float;

namespace {
constexpr int kT = 16, kH = 1024, kFH = 4096, kC = 2513, kCP = 2560;
}

__device__ __forceinline__ void gload16(const void* g, void* l) {
  __builtin_amdgcn_global_load_lds((const __attribute__((address_space(1))) void*)g,
                                   (__attribute__((address_space(3))) void*)l, 16, 0, 0);
}
__device__ __forceinline__ float sgm(float x) { return 1.0f / (1.0f + __expf(-x)); }

// ---------------- setup kernels ----------------
__global__ void cast_f2h4(const flt4v* __restrict__ s, half4v* __restrict__ d, int n4) {
  int i = blockIdx.x * 256 + threadIdx.x;
  if (i < n4) d[i] = __builtin_convertvector(s[i], half4v);
}

__global__ void pad_wc_f2h4(const flt4v* __restrict__ s, half4v* __restrict__ d) {
  int i = blockIdx.x * 256 + threadIdx.x;  // over kCP*kH/4
  if (i >= kCP * kH / 4) return;
  if (i < kC * kH / 4) {
    d[i] = __builtin_convertvector(s[i], half4v);
  } else {
    half4v z = {(_Float16)0, (_Float16)0, (_Float16)0, (_Float16)0};
    d[i] = z;
  }
}

__global__ void xpose_x(const float* __restrict__ x, half_t* __restrict__ xh) {
  int row = blockIdx.x;  // t*128+b
  int t = row >> 7, b = row & 127;
  const flt4v* src = (const flt4v*)(x + ((long)b * kT + t) * kH);
  half4v* dst = (half4v*)(xh + (long)row * kH);
  int i = threadIdx.x;  // 256 threads, kH/4 == 256
  dst[i] = __builtin_convertvector(src[i], half4v);
}

__global__ void prep_bias(const float* __restrict__ biR, const float* __restrict__ bhR,
                          const float* __restrict__ biU, const float* __restrict__ bhU,
                          const float* __restrict__ bc,
                          float* __restrict__ br, float* __restrict__ bu,
                          float* __restrict__ bcp) {
  int i = blockIdx.x * 256 + threadIdx.x;
  if (i < kFH) { br[i] = biR[i] + bhR[i]; bu[i] = biU[i] + bhU[i]; }
  if (i < kCP) bcp[i] = (i < kC) ? bc[i] : 0.0f;
}

// ---------------- fused LSTM step: pre = A@Wh^T (+xi), gates, state update ----
// Block tile: 128 rows x 32 j-cols x 4 gates (=128 N-cols). 4 waves as 2x2 of
// 64x64; N-cols c = wc*64 + gate*16 + col16, so each wave's 4 n-frags are the
// 4 gates for the same jj -> pure-register gate epilogue.
__global__ __launch_bounds__(256) void lstm_step(
    const half_t* __restrict__ A, const half_t* __restrict__ Wh,
    const float* __restrict__ xi, const float* __restrict__ Cin,
    half_t* __restrict__ Hout, float* __restrict__ Cout) {
  __shared__ __align__(16) half_t As[128 * 32];
  __shared__ __align__(16) half_t Bs[128 * 32];
  const int tid = threadIdx.x;
  const int lane = tid & 63;
  const int w = tid >> 6, wm = w >> 1, wc = w & 1;
  const int row16 = lane & 15;
  const int khalf = (lane >> 4) << 3;
  const int m0 = blockIdx.x << 7;
  const int j0 = blockIdx.y << 5;

  const int c0 = tid >> 2, ch = tid & 3;
  const int c1 = c0 + 64;
  const long aoff0 = (long)(m0 + c0) * kH + ch * 8;
  const long aoff1 = (long)(m0 + c1) * kH + ch * 8;
  auto brow = [&](int c) { return (((c >> 4) & 3) << 10) + j0 + ((c >> 6) << 4) + (c & 15); };
  const long boff0 = (long)brow(c0) * kH + ch * 8;
  const long boff1 = (long)brow(c1) * kH + ch * 8;

  f32x4 acc[4][4];
  const f32x4 z4 = {0.f, 0.f, 0.f, 0.f};
#pragma unroll
  for (int a = 0; a < 4; ++a)
#pragma unroll
    for (int b = 0; b < 4; ++b) acc[a][b] = z4;

  for (int kt = 0; kt < kH; kt += 32) {
    gload16(A + aoff0 + kt, &As[tid * 8]);
    gload16(A + aoff1 + kt, &As[(256 + tid) * 8]);
    gload16(Wh + boff0 + kt, &Bs[tid * 8]);
    gload16(Wh + boff1 + kt, &Bs[(256 + tid) * 8]);
    __syncthreads();
    half8 af[4], bf[4];
#pragma unroll
    for (int a = 0; a < 4; ++a)
      af[a] = *(const half8*)&As[((wm << 6) + (a << 4) + row16) * 32 + khalf];
#pragma unroll
    for (int b = 0; b < 4; ++b)
      bf[b] = *(const half8*)&Bs[((wc << 6) + (b << 4) + row16) * 32 + khalf];
#pragma unroll
    for (int a = 0; a < 4; ++a)
#pragma unroll
      for (int b = 0; b < 4; ++b)
        acc[a][b] = __builtin_amdgcn_mfma_f32_16x16x32_f16(af[a], bf[b], acc[a][b], 0, 0, 0);
    __syncthreads();
  }

  const int jg = j0 + (wc << 4) + row16;
#pragma unroll
  for (int a = 0; a < 4; ++a) {
    const int mb = m0 + (wm << 6) + (a << 4) + ((lane >> 4) << 2);
#pragma unroll
    for (int r = 0; r < 4; ++r) {
      const int m = mb + r;
      const long xb = (long)m * kFH + jg;
      const float pi = acc[a][0][r] + xi[xb];
      const float pf = acc[a][1][r] + xi[xb + 1024];
      const float pg = acc[a][2][r] + xi[xb + 2048];
      const float po = acc[a][3][r] + xi[xb + 3072];
      const float co = Cin[(long)m * kH + jg];
      const float cn = sgm(pf) * co + sgm(pi) * tanhf(pg);
      const float hn = sgm(po) * tanhf(cn);
      Hout[(long)m * kH + jg] = (half_t)hn;
      Cout[(long)m * kH + jg] = cn;
    }
  }
}

// ---------------- plain NT GEMM + bias -> fp32 out (input projections) -------
__global__ __launch_bounds__(256) void proj_gemm(
    const half_t* __restrict__ A, const half_t* __restrict__ W,
    const float* __restrict__ bias, float* __restrict__ out) {
  __shared__ __align__(16) half_t As[128 * 32];
  __shared__ __align__(16) half_t Bs[128 * 32];
  const int tid = threadIdx.x;
  const int lane = tid & 63;
  const int w = tid >> 6, wm = w >> 1, wc = w & 1;
  const int row16 = lane & 15;
  const int khalf = (lane >> 4) << 3;
  const int m0 = blockIdx.x << 7;
  const int n00 = blockIdx.y << 7;

  const int c0 = tid >> 2, ch = tid & 3;
  const int c1 = c0 + 64;
  const long aoff0 = (long)(m0 + c0) * kH + ch * 8;
  const long aoff1 = (long)(m0 + c1) * kH + ch * 8;
  const long boff0 = (long)(n00 + c0) * kH + ch * 8;
  const long boff1 = (long)(n00 + c1) * kH + ch * 8;

  f32x4 acc[4][4];
  const f32x4 z4 = {0.f, 0.f, 0.f, 0.f};
#pragma unroll
  for (int a = 0; a < 4; ++a)
#pragma unroll
    for (int b = 0; b < 4; ++b) acc[a][b] = z4;

  for (int kt = 0; kt < kH; kt += 32) {
    gload16(A + aoff0 + kt, &As[tid * 8]);
    gload16(A + aoff1 + kt, &As[(256 + tid) * 8]);
    gload16(W + boff0 + kt, &Bs[tid * 8]);
    gload16(W + boff1 + kt, &Bs[(256 + tid) * 8]);
    __syncthreads();
    half8 af[4], bf[4];
#pragma unroll
    for (int a = 0; a < 4; ++a)
      af[a] = *(const half8*)&As[((wm << 6) + (a << 4) + row16) * 32 + khalf];
#pragma unroll
    for (int b = 0; b < 4; ++b)
      bf[b] = *(const half8*)&Bs[((wc << 6) + (b << 4) + row16) * 32 + khalf];
#pragma unroll
    for (int a = 0; a < 4; ++a)
#pragma unroll
      for (int b = 0; b < 4; ++b)
        acc[a][b] = __builtin_amdgcn_mfma_f32_16x16x32_f16(af[a], bf[b], acc[a][b], 0, 0, 0);
    __syncthreads();
  }

#pragma unroll
  for (int a = 0; a < 4; ++a) {
    const int mb = m0 + (wm << 6) + (a << 4) + ((lane >> 4) << 2);
#pragma unroll
    for (int b = 0; b < 4; ++b) {
      const int n = n00 + (wc << 6) + (b << 4) + row16;
      const float bv = bias[n];
#pragma unroll
      for (int r = 0; r < 4; ++r) {
        out[(long)(mb + r) * kFH + n] = acc[a][b][r] + bv;
      }
    }
  }
}

// ---------------- classifier: gather-A by parity, strided store --------------
__global__ __launch_bounds__(256) void cls_gemm(
    const half_t* __restrict__ H0, const half_t* __restrict__ H1,
    const half_t* __restrict__ Wcw, const float* __restrict__ bcp,
    float* __restrict__ out) {
  __shared__ __align__(16) half_t As[128 * 32];
  __shared__ __align__(16) half_t Bs[128 * 32];
  const int tid = threadIdx.x;
  const int lane = tid & 63;
  const int w = tid >> 6, wm = w >> 1, wc = w & 1;
  const int row16 = lane & 15;
  const int khalf = (lane >> 4) << 3;
  const int t = blockIdx.x;
  const half_t* __restrict__ A = ((17 - t) & 1) ? H1 : H0;
  const int m0 = t << 7;
  const int n00 = blockIdx.y << 7;

  const int c0 = tid >> 2, ch = tid & 3;
  const int c1 = c0 + 64;
  const long aoff0 = (long)(m0 + c0) * kH + ch * 8;
  const long aoff1 = (long)(m0 + c1) * kH + ch * 8;
  const long boff0 = (long)(n00 + c0) * kH + ch * 8;
  const long boff1 = (long)(n00 + c1) * kH + ch * 8;

  f32x4 acc[4][4];
  const f32x4 z4 = {0.f, 0.f, 0.f, 0.f};
#pragma unroll
  for (int a = 0; a < 4; ++a)
#pragma unroll
    for (int b = 0; b < 4; ++b) acc[a][b] = z4;

  for (int kt = 0; kt < kH; kt += 32) {
    gload16(A + aoff0 + kt, &As[tid * 8]);
    gload16(A + aoff1 + kt, &As[(256 + tid) * 8]);
    gload16(Wcw + boff0 + kt, &Bs[tid * 8]);
    gload16(Wcw + boff1 + kt, &Bs[(256 + tid) * 8]);
    __syncthreads();
    half8 af[4], bf[4];
#pragma unroll
    for (int a = 0; a < 4; ++a)
      af[a] = *(const half8*)&As[((wm << 6) + (a << 4) + row16) * 32 + khalf];
#pragma unroll
    for (int b = 0; b < 4; ++b)
      bf[b] = *(const half8*)&Bs[((wc << 6) + (b << 4) + row16) * 32 + khalf];
#pragma unroll
    for (int a = 0; a < 4; ++a)
#pragma unroll
      for (int b = 0; b < 4; ++b)
        acc[a][b] = __builtin_amdgcn_mfma_f32_16x16x32_f16(af[a], bf[b], acc[a][b], 0, 0, 0);
    __syncthreads();
  }

#pragma unroll
  for (int a = 0; a < 4; ++a) {
    const int mb = m0 + (wm << 6) + (a << 4) + ((lane >> 4) << 2);
#pragma unroll
    for (int b = 0; b < 4; ++b) {
      const int n = n00 + (wc << 6) + (b << 4) + row16;
      if (n < kC) {
        const float bv = bcp[n];
#pragma unroll
        for (int r = 0; r < 4; ++r) {
          const int m = mb + r;
          const int bi = m & 127;
          out[((long)bi * kT + t) * kC + n] = acc[a][b][r] + bv;
        }
      }
    }
  }
}

extern "C" void kernel_launch(void* const* d_in, const int* in_sizes, int n_in,
                              void* d_out, int out_size, void* d_ws, size_t ws_size,
                              hipStream_t stream) {
  const float* x   = (const float*)d_in[0];
  const float* WiR = (const float*)d_in[1];
  const float* WhR = (const float*)d_in[2];
  const float* biR = (const float*)d_in[3];
  const float* bhR = (const float*)d_in[4];
  const float* WiU = (const float*)d_in[5];
  const float* WhU = (const float*)d_in[6];
  const float* biU = (const float*)d_in[7];
  const float* bhU = (const float*)d_in[8];
  const float* Wc  = (const float*)d_in[9];
  const float* bc  = (const float*)d_in[10];

  size_t off = 0;
  auto alloc = [&](size_t bytes) -> void* {
    void* p = (char*)d_ws + off;
    off += (bytes + 255) & ~(size_t)255;
    return p;
  };
  half_t* xh   = (half_t*)alloc((size_t)2048 * 1024 * 2);
  half_t* WiRh = (half_t*)alloc((size_t)4096 * 1024 * 2);
  half_t* WhRh = (half_t*)alloc((size_t)4096 * 1024 * 2);
  half_t* WiUh = (half_t*)alloc((size_t)4096 * 1024 * 2);
  half_t* WhUh = (half_t*)alloc((size_t)4096 * 1024 * 2);
  half_t* Wch  = (half_t*)alloc((size_t)2560 * 1024 * 2);
  float*  br   = (float*)alloc(4096 * 4);
  float*  bu   = (float*)alloc(4096 * 4);
  float*  bcp  = (float*)alloc(2560 * 4);
  float*  xiR  = (float*)alloc((size_t)2048 * 4096 * 4);
  float*  xiU  = (float*)alloc((size_t)2048 * 4096 * 4);
  half_t* HS   = (half_t*)alloc((size_t)17 * 128 * 1024 * 2);
  float*  CS   = (float*)alloc((size_t)17 * 128 * 1024 * 4);
  half_t* Ha   = (half_t*)alloc((size_t)2048 * 1024 * 2);
  half_t* Hb   = (half_t*)alloc((size_t)2048 * 1024 * 2);
  float*  Ca   = (float*)alloc((size_t)2048 * 1024 * 4);
  float*  Cb   = (float*)alloc((size_t)2048 * 1024 * 4);
  (void)ws_size; (void)in_sizes; (void)n_in; (void)out_size;

  // zero initial roll state (block 0 of HS/CS)
  hipMemsetAsync(HS, 0, (size_t)128 * 1024 * 2, stream);
  hipMemsetAsync(CS, 0, (size_t)128 * 1024 * 4, stream);

  // converts
  cast_f2h4<<<4096, 256, 0, stream>>>((const flt4v*)WiR, (half4v*)WiRh, 1048576);
  cast_f2h4<<<4096, 256, 0, stream>>>((const flt4v*)WhR, (half4v*)WhRh, 1048576);
  cast_f2h4<<<4096, 256, 0, stream>>>((const flt4v*)WiU, (half4v*)WiUh, 1048576);
  cast_f2h4<<<4096, 256, 0, stream>>>((const flt4v*)WhU, (half4v*)WhUh, 1048576);
  pad_wc_f2h4<<<2560, 256, 0, stream>>>((const flt4v*)Wc, (half4v*)Wch);
  prep_bias<<<16, 256, 0, stream>>>(biR, bhR, biU, bhU, bc, br, bu, bcp);
  xpose_x<<<2048, 256, 0, stream>>>(x, xh);

  // input projections (bias folded in)
  proj_gemm<<<dim3(16, 32), 256, 0, stream>>>(xh, WiRh, br, xiR);
  proj_gemm<<<dim3(16, 32), 256, 0, stream>>>(xh, WiUh, bu, xiU);

  // rolling LSTM: 16 steps, state blocks in HS/CS (block t -> block t+1)
  for (int t = 0; t < 16; ++t) {
    lstm_step<<<dim3(1, 32), 256, 0, stream>>>(
        HS + (size_t)t * 131072, WhRh, xiR + (size_t)t * 524288,
        CS + (size_t)t * 131072, HS + (size_t)(t + 1) * 131072,
        CS + (size_t)(t + 1) * 131072);
  }

  // unrolling LSTM: 17 steps over active prefix, ping-pong state buffers.
  // step s reads (s==1 ? roll outputs : buf[(s-1)&1]), writes buf[s&1].
  for (int s = 1; s <= 17; ++s) {
    int cnt = 18 - s;
    if (cnt > 16) cnt = 16;
    const half_t* Ain = (s == 1) ? (HS + 131072) : (((s - 1) & 1) ? Hb : Ha);
    const float* Cinp = (s == 1) ? (CS + 131072) : (((s - 1) & 1) ? Cb : Ca);
    half_t* Ho = (s & 1) ? Hb : Ha;
    float*  Co = (s & 1) ? Cb : Ca;
    lstm_step<<<dim3(cnt, 32), 256, 0, stream>>>(Ain, WhUh, xiU, Cinp, Ho, Co);
  }

  // classifier: block-row t's final h lives in buf[(17-t)&1]
  cls_gemm<<<dim3(16, 20), 256, 0, stream>>>(Ha, Hb, Wch, bcp, (float*)d_out);
}

// Round 2
// 944.608 us; speedup vs baseline: 1.1662x; 1.1662x over previous
//
#include <hip/hip_runtime.h>
#include <cstdint>

using half_t = _Float16;
using half8  = __attribute__((ext_vector_type(8))) _Float16;
using half4v = __attribute__((ext_vector_type(4))) _Float16;
using f32x4  = __attribute__((ext_vector_type(4))) float;
using flt4v  = __attribute__((ext_vector_type(4))) float;

namespace {
constexpr int kT = 16, kH = 1024, kFH = 4096, kC = 2513, kCP = 2560;
}

__device__ __forceinline__ void gload16(const void* g, void* l) {
  __builtin_amdgcn_global_load_lds((const __attribute__((address_space(1))) void*)g,
                                   (__attribute__((address_space(3))) void*)l, 16, 0, 0);
}
__device__ __forceinline__ float sgm(float x) { return 1.0f / (1.0f + __expf(-x)); }

// ---------------- setup kernels ----------------
__global__ void cast_all(const flt4v* __restrict__ WiR, const flt4v* __restrict__ WhR,
                         const flt4v* __restrict__ WiU, const flt4v* __restrict__ WhU,
                         const flt4v* __restrict__ Wc,
                         half4v* __restrict__ WiRh, half4v* __restrict__ WhRh,
                         half4v* __restrict__ WiUh, half4v* __restrict__ WhUh,
                         half4v* __restrict__ Wch) {
  long i = (long)blockIdx.x * 256 + threadIdx.x;
  const long Q = 1048576;
  if (i < Q) { WiRh[i] = __builtin_convertvector(WiR[i], half4v); return; }
  i -= Q;
  if (i < Q) { WhRh[i] = __builtin_convertvector(WhR[i], half4v); return; }
  i -= Q;
  if (i < Q) { WiUh[i] = __builtin_convertvector(WiU[i], half4v); return; }
  i -= Q;
  if (i < Q) { WhUh[i] = __builtin_convertvector(WhU[i], half4v); return; }
  i -= Q;
  if (i < (long)kCP * kH / 4) {
    if (i < (long)kC * kH / 4) {
      Wch[i] = __builtin_convertvector(Wc[i], half4v);
    } else {
      half4v z = {(_Float16)0, (_Float16)0, (_Float16)0, (_Float16)0};
      Wch[i] = z;
    }
  }
}

__global__ void xpose_x(const float* __restrict__ x, half_t* __restrict__ xh) {
  int row = blockIdx.x;  // t*128+b
  int t = row >> 7, b = row & 127;
  const flt4v* src = (const flt4v*)(x + ((long)b * kT + t) * kH);
  half4v* dst = (half4v*)(xh + (long)row * kH);
  int i = threadIdx.x;  // 256 threads, kH/4 == 256
  dst[i] = __builtin_convertvector(src[i], half4v);
}

// packed biases: br_p/bu_p [j][gate] (j in 0..1023, gate 0..3); bcp linear padded
__global__ void prep_bias(const float* __restrict__ biR, const float* __restrict__ bhR,
                          const float* __restrict__ biU, const float* __restrict__ bhU,
                          const float* __restrict__ bc,
                          float* __restrict__ br_p, float* __restrict__ bu_p,
                          float* __restrict__ bcp) {
  int i = blockIdx.x * 256 + threadIdx.x;
  if (i < kFH) {
    int j = i >> 2, gt = i & 3;
    br_p[i] = biR[gt * kH + j] + bhR[gt * kH + j];
    bu_p[i] = biU[gt * kH + j] + bhU[gt * kH + j];
  }
  if (i < kCP) bcp[i] = (i < kC) ? bc[i] : 0.0f;
}

// ---------------- shared GEMM core: 128x128 tile, K=1024, BK=64, dbuf + swizzle
// LDS layout per buffer: [128 rows][8 slots of 8 halfs]; slot holds global
// k-chunk (slot ^ (row&7)) -> ds_read_b128 2-way-conflict-free.
// Stage: thread i-iter covers row = i*32 + tid>>3, slot = tid&7; global src
// k-offset = ((tid&7) ^ (row&7))*8.
__device__ __forceinline__ void gemm_k1024(
    const half_t* __restrict__ A, const half_t* __restrict__ B,
    const long* ao, const long* bo, half_t* AsB, half_t* BsB,
    int tid, int wm, int wc, int row16, int g, f32x4 acc[4][4]) {
#pragma unroll
  for (int i = 0; i < 4; ++i) gload16(A + ao[i], AsB + (i * 256 + tid) * 8);
#pragma unroll
  for (int i = 0; i < 4; ++i) gload16(B + bo[i], BsB + (i * 256 + tid) * 8);
  __syncthreads();
  int p = 0;
  for (int kt = 64; kt <= 1024; kt += 64) {
    if (kt < 1024) {
      half_t* as_n = AsB + (p ^ 1) * 8192;
      half_t* bs_n = BsB + (p ^ 1) * 8192;
#pragma unroll
      for (int i = 0; i < 4; ++i) gload16(A + ao[i] + kt, as_n + (i * 256 + tid) * 8);
#pragma unroll
      for (int i = 0; i < 4; ++i) gload16(B + bo[i] + kt, bs_n + (i * 256 + tid) * 8);
    }
    const half_t* as_ = AsB + p * 8192;
    const half_t* bs_ = BsB + p * 8192;
#pragma unroll
    for (int s = 0; s < 2; ++s) {
      half8 af[4], bf[4];
#pragma unroll
      for (int a = 0; a < 4; ++a) {
        const int row = (wm << 6) + (a << 4) + row16;
        const int slot = (s * 4 + g) ^ (row & 7);
        af[a] = *(const half8*)&as_[row * 64 + slot * 8];
      }
#pragma unroll
      for (int b = 0; b < 4; ++b) {
        const int row = (wc << 6) + (b << 4) + row16;
        const int slot = (s * 4 + g) ^ (row & 7);
        bf[b] = *(const half8*)&bs_[row * 64 + slot * 8];
      }
#pragma unroll
      for (int a = 0; a < 4; ++a)
#pragma unroll
        for (int b = 0; b < 4; ++b)
          acc[a][b] = __builtin_amdgcn_mfma_f32_16x16x32_f16(af[a], bf[b], acc[a][b], 0, 0, 0);
    }
    __syncthreads();
    p ^= 1;
  }
}

// gate-interleaved B-row mapping: LDS B-row r -> weight row gate(r)*1024 + j0 + jj(r)
__device__ __forceinline__ int brow_gate(int r, int j0) {
  return (((r >> 4) & 3) << 10) + j0 + ((r >> 6) << 4) + (r & 15);
}

// ---------------- fused LSTM step (TAG 0 = roll, 1 = unroll) ----------------
template <int TAG>
__global__ __launch_bounds__(256) void lstm_step(
    const half_t* __restrict__ A, const half_t* __restrict__ Wh,
    const half_t* __restrict__ xi, const float* __restrict__ Cin,
    half_t* __restrict__ Hout, float* __restrict__ Cout) {
  __shared__ __align__(16) half_t As[2 * 8192];
  __shared__ __align__(16) half_t Bs[2 * 8192];
  const int tid = threadIdx.x;
  const int lane = tid & 63;
  const int w = tid >> 6, wm = w >> 1, wc = w & 1;
  const int row16 = lane & 15;
  const int g = lane >> 4;
  const int m0 = blockIdx.x << 7;
  const int j0 = blockIdx.y << 5;

  long ao[4], bo[4];
#pragma unroll
  for (int i = 0; i < 4; ++i) {
    const int row = i * 32 + (tid >> 3);
    const int kk = ((tid & 7) ^ (row & 7)) * 8;
    ao[i] = (long)(m0 + row) * kH + kk;
    bo[i] = (long)brow_gate(row, j0) * kH + kk;
  }

  f32x4 acc[4][4];
  const f32x4 z4 = {0.f, 0.f, 0.f, 0.f};
#pragma unroll
  for (int a = 0; a < 4; ++a)
#pragma unroll
    for (int b = 0; b < 4; ++b) acc[a][b] = z4;

  gemm_k1024(A, Wh, ao, bo, As, Bs, tid, wm, wc, row16, g, acc);

  const int jg = j0 + (wc << 4) + row16;
#pragma unroll
  for (int a = 0; a < 4; ++a) {
    const int mb = m0 + (wm << 6) + (a << 4) + (g << 2);
#pragma unroll
    for (int r = 0; r < 4; ++r) {
      const int m = mb + r;
      const half4v xv = *(const half4v*)&xi[((long)m * kH + jg) * 4];
      const float pi = acc[a][0][r] + (float)xv[0];
      const float pf = acc[a][1][r] + (float)xv[1];
      const float pg = acc[a][2][r] + (float)xv[2];
      const float po = acc[a][3][r] + (float)xv[3];
      const float co = Cin[(long)m * kH + jg];
      const float cn = sgm(pf) * co + sgm(pi) * tanhf(pg);
      const float hn = sgm(po) * tanhf(cn);
      Hout[(long)m * kH + jg] = (half_t)hn;
      Cout[(long)m * kH + jg] = cn;
    }
  }
}

// ---------------- input projection: out = packed fp16 xi [m][j][gate] --------
__global__ __launch_bounds__(256) void proj_gemm(
    const half_t* __restrict__ A, const half_t* __restrict__ W,
    const float* __restrict__ bias_p, half_t* __restrict__ xi) {
  __shared__ __align__(16) half_t As[2 * 8192];
  __shared__ __align__(16) half_t Bs[2 * 8192];
  const int tid = threadIdx.x;
  const int lane = tid & 63;
  const int w = tid >> 6, wm = w >> 1, wc = w & 1;
  const int row16 = lane & 15;
  const int g = lane >> 4;
  const int m0 = blockIdx.x << 7;
  const int j0 = blockIdx.y << 5;

  long ao[4], bo[4];
#pragma unroll
  for (int i = 0; i < 4; ++i) {
    const int row = i * 32 + (tid >> 3);
    const int kk = ((tid & 7) ^ (row & 7)) * 8;
    ao[i] = (long)(m0 + row) * kH + kk;
    bo[i] = (long)brow_gate(row, j0) * kH + kk;
  }

  f32x4 acc[4][4];
  const f32x4 z4 = {0.f, 0.f, 0.f, 0.f};
#pragma unroll
  for (int a = 0; a < 4; ++a)
#pragma unroll
    for (int b = 0; b < 4; ++b) acc[a][b] = z4;

  gemm_k1024(A, W, ao, bo, As, Bs, tid, wm, wc, row16, g, acc);

  const int jg = j0 + (wc << 4) + row16;
  const f32x4 bv = *(const f32x4*)&bias_p[jg * 4];
#pragma unroll
  for (int a = 0; a < 4; ++a) {
    const int mb = m0 + (wm << 6) + (a << 4) + (g << 2);
#pragma unroll
    for (int r = 0; r < 4; ++r) {
      half4v o;
      o[0] = (half_t)(acc[a][0][r] + bv[0]);
      o[1] = (half_t)(acc[a][1][r] + bv[1]);
      o[2] = (half_t)(acc[a][2][r] + bv[2]);
      o[3] = (half_t)(acc[a][3][r] + bv[3]);
      *(half4v*)&xi[((long)(mb + r) * kH + jg) * 4] = o;
    }
  }
}

// ---------------- classifier ----------------
__global__ __launch_bounds__(256) void cls_gemm(
    const half_t* __restrict__ H0, const half_t* __restrict__ H1,
    const half_t* __restrict__ Wcw, const float* __restrict__ bcp,
    float* __restrict__ out) {
  __shared__ __align__(16) half_t As[2 * 8192];
  __shared__ __align__(16) half_t Bs[2 * 8192];
  const int tid = threadIdx.x;
  const int lane = tid & 63;
  const int w = tid >> 6, wm = w >> 1, wc = w & 1;
  const int row16 = lane & 15;
  const int g = lane >> 4;
  const int t = blockIdx.x;
  const half_t* __restrict__ A = ((17 - t) & 1) ? H1 : H0;
  const int m0 = t << 7;
  const int n00 = blockIdx.y << 7;

  long ao[4], bo[4];
#pragma unroll
  for (int i = 0; i < 4; ++i) {
    const int row = i * 32 + (tid >> 3);
    const int kk = ((tid & 7) ^ (row & 7)) * 8;
    ao[i] = (long)(m0 + row) * kH + kk;
    bo[i] = (long)(n00 + row) * kH + kk;
  }

  f32x4 acc[4][4];
  const f32x4 z4 = {0.f, 0.f, 0.f, 0.f};
#pragma unroll
  for (int a = 0; a < 4; ++a)
#pragma unroll
    for (int b = 0; b < 4; ++b) acc[a][b] = z4;

  gemm_k1024(A, Wcw, ao, bo, As, Bs, tid, wm, wc, row16, g, acc);

#pragma unroll
  for (int a = 0; a < 4; ++a) {
    const int mb = m0 + (wm << 6) + (a << 4) + (g << 2);
#pragma unroll
    for (int b = 0; b < 4; ++b) {
      const int n = n00 + (wc << 6) + (b << 4) + row16;
      if (n < kC) {
        const float bvv = bcp[n];
#pragma unroll
        for (int r = 0; r < 4; ++r) {
          const int m = mb + r;
          const int bi = m & 127;
          out[((long)bi * kT + t) * kC + n] = acc[a][b][r] + bvv;
        }
      }
    }
  }
}

extern "C" void kernel_launch(void* const* d_in, const int* in_sizes, int n_in,
                              void* d_out, int out_size, void* d_ws, size_t ws_size,
                              hipStream_t stream) {
  const float* x   = (const float*)d_in[0];
  const float* WiR = (const float*)d_in[1];
  const float* WhR = (const float*)d_in[2];
  const float* biR = (const float*)d_in[3];
  const float* bhR = (const float*)d_in[4];
  const float* WiU = (const float*)d_in[5];
  const float* WhU = (const float*)d_in[6];
  const float* biU = (const float*)d_in[7];
  const float* bhU = (const float*)d_in[8];
  const float* Wc  = (const float*)d_in[9];
  const float* bc  = (const float*)d_in[10];

  size_t off = 0;
  auto alloc = [&](size_t bytes) -> void* {
    void* p = (char*)d_ws + off;
    off += (bytes + 255) & ~(size_t)255;
    return p;
  };
  half_t* xh   = (half_t*)alloc((size_t)2048 * 1024 * 2);
  half_t* WiRh = (half_t*)alloc((size_t)4096 * 1024 * 2);
  half_t* WhRh = (half_t*)alloc((size_t)4096 * 1024 * 2);
  half_t* WiUh = (half_t*)alloc((size_t)4096 * 1024 * 2);
  half_t* WhUh = (half_t*)alloc((size_t)4096 * 1024 * 2);
  half_t* Wch  = (half_t*)alloc((size_t)2560 * 1024 * 2);
  float*  br   = (float*)alloc(4096 * 4);
  float*  bu   = (float*)alloc(4096 * 4);
  float*  bcp  = (float*)alloc(2560 * 4);
  half_t* xiR  = (half_t*)alloc((size_t)2048 * 4096 * 2);
  half_t* xiU  = (half_t*)alloc((size_t)2048 * 4096 * 2);
  half_t* HS   = (half_t*)alloc((size_t)17 * 128 * 1024 * 2);
  float*  CS   = (float*)alloc((size_t)17 * 128 * 1024 * 4);
  half_t* Ha   = (half_t*)alloc((size_t)2048 * 1024 * 2);
  half_t* Hb   = (half_t*)alloc((size_t)2048 * 1024 * 2);
  float*  Ca   = (float*)alloc((size_t)2048 * 1024 * 4);
  float*  Cb   = (float*)alloc((size_t)2048 * 1024 * 4);
  (void)ws_size; (void)in_sizes; (void)n_in; (void)out_size;

  // zero initial roll state (block 0 of HS/CS)
  hipMemsetAsync(HS, 0, (size_t)128 * 1024 * 2, stream);
  hipMemsetAsync(CS, 0, (size_t)128 * 1024 * 4, stream);

  // setup: weight casts + bias pack + x transpose
  cast_all<<<18944, 256, 0, stream>>>((const flt4v*)WiR, (const flt4v*)WhR,
                                      (const flt4v*)WiU, (const flt4v*)WhU,
                                      (const flt4v*)Wc, (half4v*)WiRh, (half4v*)WhRh,
                                      (half4v*)WiUh, (half4v*)WhUh, (half4v*)Wch);
  prep_bias<<<16, 256, 0, stream>>>(biR, bhR, biU, bhU, bc, br, bu, bcp);
  xpose_x<<<2048, 256, 0, stream>>>(x, xh);

  // input projections -> packed fp16 xi [m][j][gate]
  proj_gemm<<<dim3(16, 32), 256, 0, stream>>>(xh, WiRh, br, xiR);
  proj_gemm<<<dim3(16, 32), 256, 0, stream>>>(xh, WiUh, bu, xiU);

  // rolling LSTM: 16 steps, state blocks in HS/CS (block t -> block t+1)
  for (int t = 0; t < 16; ++t) {
    lstm_step<0><<<dim3(1, 32), 256, 0, stream>>>(
        HS + (size_t)t * 131072, WhRh, xiR + (size_t)t * 524288,
        CS + (size_t)t * 131072, HS + (size_t)(t + 1) * 131072,
        CS + (size_t)(t + 1) * 131072);
  }

  // unrolling LSTM: 17 steps over active prefix, ping-pong state buffers.
  for (int s = 1; s <= 17; ++s) {
    int cnt = 18 - s;
    if (cnt > 16) cnt = 16;
    const half_t* Ain = (s == 1) ? (HS + 131072) : (((s - 1) & 1) ? Hb : Ha);
    const float* Cinp = (s == 1) ? (CS + 131072) : (((s - 1) & 1) ? Cb : Ca);
    half_t* Ho = (s & 1) ? Hb : Ha;
    float*  Co = (s & 1) ? Cb : Ca;
    lstm_step<1><<<dim3(cnt, 32), 256, 0, stream>>>(Ain, WhUh, xiU, Cinp, Ho, Co);
  }

  // classifier: block-row t's final h lives in buf[(17-t)&1]
  cls_gemm<<<dim3(16, 20), 256, 0, stream>>>(Ha, Hb, Wch, bcp, (float*)d_out);
}

// Round 3
// 572.931 us; speedup vs baseline: 1.9228x; 1.6487x over previous
//
#include <hip/hip_runtime.h>
#include <cstdint>

using half_t = _Float16;
using half8  = __attribute__((ext_vector_type(8))) _Float16;
using half4v = __attribute__((ext_vector_type(4))) _Float16;
using f32x4  = __attribute__((ext_vector_type(4))) float;
using flt4v  = __attribute__((ext_vector_type(4))) float;

namespace {
constexpr int kT = 16, kH = 1024, kFH = 4096, kC = 2513, kCP = 2560;
constexpr int kSlot = 128 * 1024;   // elements per state slot (128 rows x 1024)
constexpr int kPar  = 17 * kSlot;   // elements per parity plane
}

__device__ __forceinline__ void gload16(const void* g, void* l) {
  __builtin_amdgcn_global_load_lds((const __attribute__((address_space(1))) void*)g,
                                   (__attribute__((address_space(3))) void*)l, 16, 0, 0);
}
__device__ __forceinline__ float sgm(float x) { return 1.0f / (1.0f + __expf(-x)); }

// ---------------- fused setup: weight casts + x transpose + bias packs -------
__global__ void setup_all(const flt4v* __restrict__ WiR, const flt4v* __restrict__ WhR,
                          const flt4v* __restrict__ WiU, const flt4v* __restrict__ WhU,
                          const flt4v* __restrict__ Wc, const float* __restrict__ x,
                          const float* __restrict__ biR, const float* __restrict__ bhR,
                          const float* __restrict__ biU, const float* __restrict__ bhU,
                          const float* __restrict__ bc,
                          half4v* __restrict__ WiRh, half4v* __restrict__ WhRh,
                          half4v* __restrict__ WiUh, half4v* __restrict__ WhUh,
                          half4v* __restrict__ Wch, half_t* __restrict__ xh,
                          float* __restrict__ br_p, float* __restrict__ bu_p,
                          float* __restrict__ bcp) {
  int blk = blockIdx.x;
  if (blk < 18944) {  // weight casts, 1024 f32 elements (256 x flt4v) per block
    long i = (long)blk * 256 + threadIdx.x;
    const long Q = 1048576;
    if (i < Q) { WiRh[i] = __builtin_convertvector(WiR[i], half4v); return; }
    i -= Q;
    if (i < Q) { WhRh[i] = __builtin_convertvector(WhR[i], half4v); return; }
    i -= Q;
    if (i < Q) { WiUh[i] = __builtin_convertvector(WiU[i], half4v); return; }
    i -= Q;
    if (i < Q) { WhUh[i] = __builtin_convertvector(WhU[i], half4v); return; }
    i -= Q;
    if (i < (long)kC * kH / 4) {
      Wch[i] = __builtin_convertvector(Wc[i], half4v);
    } else if (i < (long)kCP * kH / 4) {
      half4v z = {(_Float16)0, (_Float16)0, (_Float16)0, (_Float16)0};
      Wch[i] = z;
    }
    return;
  }
  blk -= 18944;
  if (blk < 2048) {  // x transpose [B,T,F] -> [t*128+b][F], fp16
    int t = blk >> 7, b = blk & 127;
    const flt4v* src = (const flt4v*)(x + ((long)b * kT + t) * kH);
    half4v* dst = (half4v*)(xh + (long)blk * kH);
    dst[threadIdx.x] = __builtin_convertvector(src[threadIdx.x], half4v);
    return;
  }
  blk -= 2048;
  {  // bias packs: br_p/bu_p [j][gate]; bcp padded linear
    int i = blk * 256 + threadIdx.x;
    if (i < kFH) {
      int j = i >> 2, gt = i & 3;
      br_p[i] = biR[gt * kH + j] + bhR[gt * kH + j];
      bu_p[i] = biU[gt * kH + j] + bhU[gt * kH + j];
    }
    if (i < kCP) bcp[i] = (i < kC) ? bc[i] : 0.0f;
  }
}

// ---------------- shared GEMM core: 128x128 tile, K=1024, BK=64, dbuf + swizzle
// LDS per buffer: [128 rows][8 slots of 8 halfs]; slot s holds global k-chunk
// (s ^ (row&7)) -> ds_read_b128 2-way-conflict-free (free per m136).
__device__ __forceinline__ void gemm_k1024(
    const half_t* __restrict__ A, const half_t* __restrict__ B,
    const long* ao, const long* bo, half_t* AsB, half_t* BsB,
    int tid, int wm, int wc, int row16, int g, f32x4 acc[4][4]) {
#pragma unroll
  for (int i = 0; i < 4; ++i) gload16(A + ao[i], AsB + (i * 256 + tid) * 8);
#pragma unroll
  for (int i = 0; i < 4; ++i) gload16(B + bo[i], BsB + (i * 256 + tid) * 8);
  __syncthreads();
  int p = 0;
  for (int kt = 64; kt <= 1024; kt += 64) {
    if (kt < 1024) {
      half_t* as_n = AsB + (p ^ 1) * 8192;
      half_t* bs_n = BsB + (p ^ 1) * 8192;
#pragma unroll
      for (int i = 0; i < 4; ++i) gload16(A + ao[i] + kt, as_n + (i * 256 + tid) * 8);
#pragma unroll
      for (int i = 0; i < 4; ++i) gload16(B + bo[i] + kt, bs_n + (i * 256 + tid) * 8);
    }
    const half_t* as_ = AsB + p * 8192;
    const half_t* bs_ = BsB + p * 8192;
#pragma unroll
    for (int s = 0; s < 2; ++s) {
      half8 af[4], bf[4];
#pragma unroll
      for (int a = 0; a < 4; ++a) {
        const int row = (wm << 6) + (a << 4) + row16;
        const int slot = (s * 4 + g) ^ (row & 7);
        af[a] = *(const half8*)&as_[row * 64 + slot * 8];
      }
#pragma unroll
      for (int b = 0; b < 4; ++b) {
        const int row = (wc << 6) + (b << 4) + row16;
        const int slot = (s * 4 + g) ^ (row & 7);
        bf[b] = *(const half8*)&bs_[row * 64 + slot * 8];
      }
#pragma unroll
      for (int a = 0; a < 4; ++a)
#pragma unroll
        for (int b = 0; b < 4; ++b)
          acc[a][b] = __builtin_amdgcn_mfma_f32_16x16x32_f16(af[a], bf[b], acc[a][b], 0, 0, 0);
    }
    __syncthreads();
    p ^= 1;
  }
}

// gate-interleaved B-row mapping: LDS B-row r -> weight row gate(r)*1024 + j0 + jj(r)
__device__ __forceinline__ int brow_gate(int r, int j0) {
  return (((r >> 4) & 3) << 10) + j0 + ((r >> 6) << 4) + (r & 15);
}

// ---------------- pipelined recurrence step (roll + active unroll chains) ----
// Global step u (1..18). Segment sx: roll (if u<=16, sx==0) else chain c.
// Chains read parity (u&1)^1, write parity u&1. Roll at u reads chain slot
// u-2 (its own previous output) and seeds chain slot u-1. All chains take
// their final step at u=18, leaving finals in parity-0 slots 0..15.
__global__ __launch_bounds__(256) void pipe_step(
    const int u,
    const half_t* __restrict__ Wr, const half_t* __restrict__ Wu,
    const half_t* __restrict__ xiR, const half_t* __restrict__ xiU,
    half_t* __restrict__ Hbuf, float* __restrict__ Cbuf) {
  __shared__ __align__(16) half_t As[2 * 8192];
  __shared__ __align__(16) half_t Bs[2 * 8192];
  const int tid = threadIdx.x;
  const int lane = tid & 63;
  const int w = tid >> 6, wm = w >> 1, wc = w & 1;
  const int row16 = lane & 15;
  const int g = lane >> 4;
  const int j0 = blockIdx.x << 5;   // j-tile in blockIdx.x -> XCD = j%8 locality
  const int sx = blockIdx.y;

  const bool isRoll = (u <= 16) && (sx == 0);
  const int c = (u <= 16) ? (sx - 1) : sx;
  const int pr = (u & 1) ^ 1, pw = u & 1;
  const int slot_in_raw = isRoll ? (u - 2) : c;
  const bool zeroA = (slot_in_raw < 0);
  const int slot_in = zeroA ? 0 : slot_in_raw;
  const int slot_out = isRoll ? (u - 1) : c;
  const half_t* A  = Hbuf + (size_t)pr * kPar + (size_t)slot_in * kSlot;
  const float* Cin = Cbuf + (size_t)pr * kPar + (size_t)slot_in * kSlot;
  half_t* Ho = Hbuf + (size_t)pw * kPar + (size_t)slot_out * kSlot;
  float*  Co = Cbuf + (size_t)pw * kPar + (size_t)slot_out * kSlot;
  const half_t* W  = isRoll ? Wr : Wu;
  const half_t* xi = isRoll ? (xiR + (size_t)(u - 1) * 524288)
                            : (xiU + (size_t)c * 524288);

  f32x4 acc[4][4];
  const f32x4 z4 = {0.f, 0.f, 0.f, 0.f};
#pragma unroll
  for (int a = 0; a < 4; ++a)
#pragma unroll
    for (int b = 0; b < 4; ++b) acc[a][b] = z4;

  if (!zeroA) {
    long ao[4], bo[4];
#pragma unroll
    for (int i = 0; i < 4; ++i) {
      const int row = i * 32 + (tid >> 3);
      const int kk = ((tid & 7) ^ (row & 7)) * 8;
      ao[i] = (long)row * kH + kk;
      bo[i] = (long)brow_gate(row, j0) * kH + kk;
    }
    gemm_k1024(A, W, ao, bo, As, Bs, tid, wm, wc, row16, g, acc);
  }

  const int jg = j0 + (wc << 4) + row16;
#pragma unroll
  for (int a = 0; a < 4; ++a) {
    const int mb = (wm << 6) + (a << 4) + (g << 2);
#pragma unroll
    for (int r = 0; r < 4; ++r) {
      const int m = mb + r;
      const half4v xv = *(const half4v*)&xi[((long)m * kH + jg) * 4];
      const float pi = acc[a][0][r] + (float)xv[0];
      const float pf = acc[a][1][r] + (float)xv[1];
      const float pg = acc[a][2][r] + (float)xv[2];
      const float po = acc[a][3][r] + (float)xv[3];
      const float co = zeroA ? 0.0f : Cin[(long)m * kH + jg];
      const float cn = sgm(pf) * co + sgm(pi) * tanhf(pg);
      const float hn = sgm(po) * tanhf(cn);
      Ho[(long)m * kH + jg] = (half_t)hn;
      Co[(long)m * kH + jg] = cn;
    }
  }
}

// ---------------- input projections (both LSTMs in one dispatch, z selects) --
__global__ __launch_bounds__(256) void proj_gemm(
    const half_t* __restrict__ Ax,
    const half_t* __restrict__ WR, const half_t* __restrict__ WU,
    const float* __restrict__ brp, const float* __restrict__ bup,
    half_t* __restrict__ xiR, half_t* __restrict__ xiU) {
  __shared__ __align__(16) half_t As[2 * 8192];
  __shared__ __align__(16) half_t Bs[2 * 8192];
  const int tid = threadIdx.x;
  const int lane = tid & 63;
  const int w = tid >> 6, wm = w >> 1, wc = w & 1;
  const int row16 = lane & 15;
  const int g = lane >> 4;
  const int j0 = blockIdx.x << 5;
  const int m0 = blockIdx.y << 7;
  const int z = blockIdx.z;
  const half_t* Wt = z ? WU : WR;
  const float* bias_p = z ? bup : brp;
  half_t* xi = z ? xiU : xiR;

  long ao[4], bo[4];
#pragma unroll
  for (int i = 0; i < 4; ++i) {
    const int row = i * 32 + (tid >> 3);
    const int kk = ((tid & 7) ^ (row & 7)) * 8;
    ao[i] = (long)(m0 + row) * kH + kk;
    bo[i] = (long)brow_gate(row, j0) * kH + kk;
  }

  f32x4 acc[4][4];
  const f32x4 z4 = {0.f, 0.f, 0.f, 0.f};
#pragma unroll
  for (int a = 0; a < 4; ++a)
#pragma unroll
    for (int b = 0; b < 4; ++b) acc[a][b] = z4;

  gemm_k1024(Ax, Wt, ao, bo, As, Bs, tid, wm, wc, row16, g, acc);

  const int jg = j0 + (wc << 4) + row16;
  const f32x4 bv = *(const f32x4*)&bias_p[jg * 4];
#pragma unroll
  for (int a = 0; a < 4; ++a) {
    const int mb = m0 + (wm << 6) + (a << 4) + (g << 2);
#pragma unroll
    for (int r = 0; r < 4; ++r) {
      half4v o;
      o[0] = (half_t)(acc[a][0][r] + bv[0]);
      o[1] = (half_t)(acc[a][1][r] + bv[1]);
      o[2] = (half_t)(acc[a][2][r] + bv[2]);
      o[3] = (half_t)(acc[a][3][r] + bv[3]);
      *(half4v*)&xi[((long)(mb + r) * kH + jg) * 4] = o;
    }
  }
}

// ---------------- classifier: A = parity-0 plane of Hbuf ([16][128][1024]) ---
__global__ __launch_bounds__(256) void cls_gemm(
    const half_t* __restrict__ Hfin, const half_t* __restrict__ Wcw,
    const float* __restrict__ bcp, float* __restrict__ out) {
  __shared__ __align__(16) half_t As[2 * 8192];
  __shared__ __align__(16) half_t Bs[2 * 8192];
  const int tid = threadIdx.x;
  const int lane = tid & 63;
  const int w = tid >> 6, wm = w >> 1, wc = w & 1;
  const int row16 = lane & 15;
  const int g = lane >> 4;
  const int n00 = blockIdx.x << 7;
  const int t = blockIdx.y;
  const int m0 = t << 7;

  long ao[4], bo[4];
#pragma unroll
  for (int i = 0; i < 4; ++i) {
    const int row = i * 32 + (tid >> 3);
    const int kk = ((tid & 7) ^ (row & 7)) * 8;
    ao[i] = (long)(m0 + row) * kH + kk;
    bo[i] = (long)(n00 + row) * kH + kk;
  }

  f32x4 acc[4][4];
  const f32x4 z4 = {0.f, 0.f, 0.f, 0.f};
#pragma unroll
  for (int a = 0; a < 4; ++a)
#pragma unroll
    for (int b = 0; b < 4; ++b) acc[a][b] = z4;

  gemm_k1024(Hfin, Wcw, ao, bo, As, Bs, tid, wm, wc, row16, g, acc);

#pragma unroll
  for (int a = 0; a < 4; ++a) {
    const int mb = m0 + (wm << 6) + (a << 4) + (g << 2);
#pragma unroll
    for (int b = 0; b < 4; ++b) {
      const int n = n00 + (wc << 6) + (b << 4) + row16;
      if (n < kC) {
        const float bvv = bcp[n];
#pragma unroll
        for (int r = 0; r < 4; ++r) {
          const int m = mb + r;
          const int bi = m & 127;
          out[((long)bi * kT + t) * kC + n] = acc[a][b][r] + bvv;
        }
      }
    }
  }
}

extern "C" void kernel_launch(void* const* d_in, const int* in_sizes, int n_in,
                              void* d_out, int out_size, void* d_ws, size_t ws_size,
                              hipStream_t stream) {
  const float* x   = (const float*)d_in[0];
  const float* WiR = (const float*)d_in[1];
  const float* WhR = (const float*)d_in[2];
  const float* biR = (const float*)d_in[3];
  const float* bhR = (const float*)d_in[4];
  const float* WiU = (const float*)d_in[5];
  const float* WhU = (const float*)d_in[6];
  const float* biU = (const float*)d_in[7];
  const float* bhU = (const float*)d_in[8];
  const float* Wc  = (const float*)d_in[9];
  const float* bc  = (const float*)d_in[10];

  size_t off = 0;
  auto alloc = [&](size_t bytes) -> void* {
    void* p = (char*)d_ws + off;
    off += (bytes + 255) & ~(size_t)255;
    return p;
  };
  half_t* xh   = (half_t*)alloc((size_t)2048 * 1024 * 2);
  half_t* WiRh = (half_t*)alloc((size_t)4096 * 1024 * 2);
  half_t* WhRh = (half_t*)alloc((size_t)4096 * 1024 * 2);
  half_t* WiUh = (half_t*)alloc((size_t)4096 * 1024 * 2);
  half_t* WhUh = (half_t*)alloc((size_t)4096 * 1024 * 2);
  half_t* Wch  = (half_t*)alloc((size_t)2560 * 1024 * 2);
  float*  br   = (float*)alloc(4096 * 4);
  float*  bu   = (float*)alloc(4096 * 4);
  float*  bcp  = (float*)alloc(2560 * 4);
  half_t* xiR  = (half_t*)alloc((size_t)2048 * 4096 * 2);
  half_t* xiU  = (half_t*)alloc((size_t)2048 * 4096 * 2);
  half_t* Hbuf = (half_t*)alloc((size_t)2 * kPar * 2);
  float*  Cbuf = (float*)alloc((size_t)2 * kPar * 4);
  (void)ws_size; (void)in_sizes; (void)n_in; (void)out_size;

  // setup: weight casts + x transpose + bias packs (one dispatch)
  setup_all<<<21008, 256, 0, stream>>>(
      (const flt4v*)WiR, (const flt4v*)WhR, (const flt4v*)WiU, (const flt4v*)WhU,
      (const flt4v*)Wc, x, biR, bhR, biU, bhU, bc,
      (half4v*)WiRh, (half4v*)WhRh, (half4v*)WiUh, (half4v*)WhUh, (half4v*)Wch,
      xh, br, bu, bcp);

  // input projections -> packed fp16 xi [m][j][gate], both LSTMs in one go
  proj_gemm<<<dim3(32, 16, 2), 256, 0, stream>>>(xh, WiRh, WiUh, br, bu, xiR, xiU);

  // pipelined recurrences: 18 global steps
  for (int u = 1; u <= 18; ++u) {
    int nchain = (u >= 2) ? ((u - 2 < 15 ? u - 2 : 15) + 1) : 0;
    int nseg = (u <= 16 ? 1 : 0) + nchain;
    pipe_step<<<dim3(32, nseg), 256, 0, stream>>>(u, WhRh, WhUh, xiR, xiU, Hbuf, Cbuf);
  }

  // classifier: finals are parity-0 slots 0..15 = [16][128][1024] contiguous
  cls_gemm<<<dim3(20, 16), 256, 0, stream>>>(Hbuf, Wch, bcp, (float*)d_out);
}